// Round 5
// baseline (234.412 us; speedup 1.0000x reference)
//
#include <hip/hip_runtime.h>

#define NB 4
#define SEQ 16384
#define D 64
#define NH 8
#define INNER 512

typedef float f4 __attribute__((ext_vector_type(4)));

// ws float-offsets
#define OFF_S  0                       // [NB][64][64]   S = K^T V
#define OFF_GT (NB * 4096)             // [NB][64][64]   GT[e][d] = G[d][e]
#define OFF_U  (2 * NB * 4096)         // [NB][NH][64][64]  U = Wk_h S Wk_h^T

// ---------------------------------------------------------------------------
// kA: S[b] += K^T V over this block's 64 rows. 1024 blocks (256/batch),
// 256 thr, thread (di,ej) owns 4x4 output tile with CONTIGUOUS f4 loads.
// No LDS; disjoint per-thread tiles -> direct atomicAdd (256 adds/address).
// ---------------------------------------------------------------------------
__global__ __launch_bounds__(256) void kA(const float* __restrict__ keys,
                                          const float* __restrict__ values,
                                          float* __restrict__ S) {
    const int bid = blockIdx.x;
    const int b = bid >> 8;
    const int row0 = (bid & 255) * 64;
    const int t = threadIdx.x;
    const int di = t >> 4, ej = t & 15;
    const float* kp = keys   + ((size_t)b * SEQ + row0) * D + di * 4;
    const float* vp = values + ((size_t)b * SEQ + row0) * D + ej * 4;
    f4 acc[4];
    #pragma unroll
    for (int r = 0; r < 4; ++r) acc[r] = (f4)0.f;
    #pragma unroll 8
    for (int n = 0; n < 64; ++n) {
        f4 k4 = *(const f4*)(kp + n * D);
        f4 v4 = *(const f4*)(vp + n * D);
        #pragma unroll
        for (int r = 0; r < 4; ++r)
            acc[r] += k4[r] * v4;
    }
    float* Sb = S + b * 4096;
    #pragma unroll
    for (int r = 0; r < 4; ++r)
        #pragma unroll
        for (int c = 0; c < 4; ++c)
            atomicAdd(&Sb[(di * 4 + r) * 64 + ej * 4 + c], acc[r][c]);
}

// ---------------------------------------------------------------------------
// kC1: U[b,h] = Wk_h @ S[b] @ Wk_h^T.  32 blocks (b,h), 256 thr (16x16 grid,
// 4x4 tiles). Operands f4 from global (L1-resident); intermediate T in LDS
// stride-65 + di-rotated columns (2-way banks = free).
// ---------------------------------------------------------------------------
__global__ __launch_bounds__(256) void kC1(const float* __restrict__ Wk,
                                           float* __restrict__ ws) {
    __shared__ float T[64 * 65];
    const int b = blockIdx.x >> 3, h = blockIdx.x & 7;
    const int t = threadIdx.x;
    const int di = t >> 4, ej = t & 15;
    const float* Sb  = ws + OFF_S + b * 4096;
    const float* Wkh = Wk + (size_t)h * 64 * D;

    // m1: T[d][i] = sum_j Wk_h[d][j] * S[j][i]
    f4 acc[4];
    #pragma unroll
    for (int r = 0; r < 4; ++r) acc[r] = (f4)0.f;
    for (int j4 = 0; j4 < 16; ++j4) {
        f4 ak[4], bs[4];
        #pragma unroll
        for (int r = 0; r < 4; ++r)  ak[r] = *(const f4*)(Wkh + (di * 4 + r) * D + j4 * 4);
        #pragma unroll
        for (int jj = 0; jj < 4; ++jj) bs[jj] = *(const f4*)(Sb + (j4 * 4 + jj) * D + ej * 4);
        #pragma unroll
        for (int r = 0; r < 4; ++r)
            #pragma unroll
            for (int jj = 0; jj < 4; ++jj)
                acc[r] += ak[r][jj] * bs[jj];
    }
    #pragma unroll
    for (int r = 0; r < 4; ++r)
        #pragma unroll
        for (int c = 0; c < 4; ++c)
            T[(di * 4 + r) * 65 + ej * 4 + ((c + di) & 3)] = acc[r][c];
    __syncthreads();

    // m2: U[d][e] = sum_i T[d][i] * Wk_h[e][i]
    float a2[4][4];
    #pragma unroll
    for (int r = 0; r < 4; ++r)
        #pragma unroll
        for (int c = 0; c < 4; ++c) a2[r][c] = 0.f;
    for (int i4 = 0; i4 < 16; ++i4) {
        float av[4][4];
        f4 bw[4];
        #pragma unroll
        for (int ii = 0; ii < 4; ++ii)
            #pragma unroll
            for (int r = 0; r < 4; ++r)
                av[r][ii] = T[(di * 4 + r) * 65 + i4 * 4 + ((ii + di) & 3)];
        #pragma unroll
        for (int c = 0; c < 4; ++c)
            bw[c] = *(const f4*)(Wkh + (ej * 4 + c) * D + i4 * 4);
        #pragma unroll
        for (int r = 0; r < 4; ++r)
            #pragma unroll
            for (int c = 0; c < 4; ++c)
                #pragma unroll
                for (int ii = 0; ii < 4; ++ii)
                    a2[r][c] = fmaf(av[r][ii], bw[c][ii], a2[r][c]);
    }
    float* Up = ws + OFF_U + (size_t)(b * 8 + h) * 4096;
    #pragma unroll
    for (int r = 0; r < 4; ++r) {
        f4 o; o[0] = a2[r][0]; o[1] = a2[r][1]; o[2] = a2[r][2]; o[3] = a2[r][3];
        *(f4*)(Up + (di * 4 + r) * 64 + ej * 4) = o;
    }
}

// ---------------------------------------------------------------------------
// kC2: GT[b] += (1/N) * (Wq_h^T U[b,h] Wout_h^T)^T.  32 blocks (b,h).
// ---------------------------------------------------------------------------
__global__ __launch_bounds__(256) void kC2(const float* __restrict__ Wq,
                                           const float* __restrict__ Wout,
                                           float* __restrict__ ws) {
    __shared__ float T[64 * 65];
    const int b = blockIdx.x >> 3, h = blockIdx.x & 7;
    const int t = threadIdx.x;
    const int di = t >> 4, ej = t & 15;
    const float* Up = ws + OFF_U + (size_t)(b * 8 + h) * 4096;

    // m3: M3[d][e] = sum_i Wq[64h+i][d] * U[i][e]
    float acc[4][4];
    #pragma unroll
    for (int r = 0; r < 4; ++r)
        #pragma unroll
        for (int c = 0; c < 4; ++c) acc[r][c] = 0.f;
    for (int i4 = 0; i4 < 16; ++i4) {
        f4 wq4[4], bu[4];
        #pragma unroll
        for (int ii = 0; ii < 4; ++ii) {
            wq4[ii] = *(const f4*)(Wq + (size_t)(64 * h + i4 * 4 + ii) * D + di * 4);
            bu[ii]  = *(const f4*)(Up + (i4 * 4 + ii) * 64 + ej * 4);
        }
        #pragma unroll
        for (int r = 0; r < 4; ++r)
            #pragma unroll
            for (int c = 0; c < 4; ++c)
                #pragma unroll
                for (int ii = 0; ii < 4; ++ii)
                    acc[r][c] = fmaf(wq4[ii][r], bu[ii][c], acc[r][c]);
    }
    #pragma unroll
    for (int r = 0; r < 4; ++r)
        #pragma unroll
        for (int c = 0; c < 4; ++c)
            T[(di * 4 + r) * 65 + ej * 4 + ((c + di) & 3)] = acc[r][c];
    __syncthreads();

    // m4: Y[d][e] = sum_i M3[d][i] * Wout[e][64h+i]; GT[e][d] += Y/N
    float a2[4][4];
    #pragma unroll
    for (int r = 0; r < 4; ++r)
        #pragma unroll
        for (int c = 0; c < 4; ++c) a2[r][c] = 0.f;
    for (int i4 = 0; i4 < 16; ++i4) {
        float av[4][4];
        f4 bw[4];
        #pragma unroll
        for (int ii = 0; ii < 4; ++ii)
            #pragma unroll
            for (int r = 0; r < 4; ++r)
                av[r][ii] = T[(di * 4 + r) * 65 + i4 * 4 + ((ii + di) & 3)];
        #pragma unroll
        for (int c = 0; c < 4; ++c)
            bw[c] = *(const f4*)(Wout + (size_t)(ej * 4 + c) * INNER + 64 * h + i4 * 4);
        #pragma unroll
        for (int r = 0; r < 4; ++r)
            #pragma unroll
            for (int c = 0; c < 4; ++c)
                #pragma unroll
                for (int ii = 0; ii < 4; ++ii)
                    a2[r][c] = fmaf(av[r][ii], bw[c][ii], a2[r][c]);
    }
    const float invn = 1.0f / (float)SEQ;
    float* GTb = ws + OFF_GT + b * 4096;
    #pragma unroll
    for (int r = 0; r < 4; ++r)
        #pragma unroll
        for (int c = 0; c < 4; ++c)
            atomicAdd(&GTb[(ej * 4 + c) * 64 + di * 4 + r], a2[r][c] * invn);
}

// ---------------------------------------------------------------------------
// kE: out[n][e] = q[n][:] . G[:][e] + bout[e] via GT (f4 over d, L1-resident).
// 1024 blocks x 64 rows, no LDS. Lane tile: 4 contiguous rows x 4 cols.
// ---------------------------------------------------------------------------
__global__ __launch_bounds__(256) void kE(const float* __restrict__ queries,
                                          const float* __restrict__ bout,
                                          const float* __restrict__ ws,
                                          float* __restrict__ out) {
    const int bid = blockIdx.x;
    const int b = bid >> 8;
    const int row0 = (bid & 255) * 64;
    const int t = threadIdx.x;
    const int w = t >> 6, l = t & 63;
    const int rg = l >> 4, eg = l & 15;
    const float* GT = ws + OFF_GT + b * 4096;
    const size_t rbase = (size_t)b * SEQ + row0 + w * 16 + rg * 4;
    const float* qp = queries + rbase * D;
    float acc[4][4];
    #pragma unroll
    for (int r = 0; r < 4; ++r)
        #pragma unroll
        for (int c = 0; c < 4; ++c) acc[r][c] = 0.f;
    #pragma unroll 2
    for (int dq = 0; dq < 16; ++dq) {
        f4 q4[4], g4[4];
        #pragma unroll
        for (int r = 0; r < 4; ++r)
            q4[r] = *(const f4*)(qp + r * D + dq * 4);
        #pragma unroll
        for (int c = 0; c < 4; ++c)
            g4[c] = *(const f4*)(GT + (eg * 4 + c) * 64 + dq * 4);
        #pragma unroll
        for (int r = 0; r < 4; ++r)
            #pragma unroll
            for (int c = 0; c < 4; ++c)
                #pragma unroll
                for (int ii = 0; ii < 4; ++ii)
                    acc[r][c] = fmaf(q4[r][ii], g4[c][ii], acc[r][c]);
    }
    const f4 bo = *(const f4*)(bout + eg * 4);
    float* op = out + rbase * D;
    #pragma unroll
    for (int r = 0; r < 4; ++r) {
        f4 o;
        o[0] = acc[r][0] + bo[0]; o[1] = acc[r][1] + bo[1];
        o[2] = acc[r][2] + bo[2]; o[3] = acc[r][3] + bo[3];
        *(f4*)(op + r * D + eg * 4) = o;
    }
}

extern "C" void kernel_launch(void* const* d_in, const int* in_sizes, int n_in,
                              void* d_out, int out_size, void* d_ws, size_t ws_size,
                              hipStream_t stream) {
    const float* queries = (const float*)d_in[0];
    const float* keys    = (const float*)d_in[1];
    const float* values  = (const float*)d_in[2];
    const float* Wq      = (const float*)d_in[3];
    const float* Wk      = (const float*)d_in[4];
    const float* Wout    = (const float*)d_in[5];
    const float* bout    = (const float*)d_in[6];
    float* ws = (float*)d_ws;

    // zero S + GT (atomic accumulation targets)
    hipMemsetAsync(ws, 0, (size_t)2 * NB * 4096 * sizeof(float), stream);

    kA <<<1024, 256, 0, stream>>>(keys, values, ws + OFF_S);
    kC1<<<32,   256, 0, stream>>>(Wk, ws);
    kC2<<<32,   256, 0, stream>>>(Wq, Wout, ws);
    kE <<<1024, 256, 0, stream>>>(queries, bout, ws, (float*)d_out);
}

// Round 8
// 184.269 us; speedup vs baseline: 1.2721x; 1.2721x over previous
//
#include <hip/hip_runtime.h>

#define NB 4
#define SEQ 16384
#define D 64
#define NH 8
#define INNER 512

typedef float f4 __attribute__((ext_vector_type(4)));

// ws float-offsets
#define OFF_S    0                           // [NB][64][64]      S = K^T V
#define OFF_GT   (NB * 4096)                 // [NB][64][64]      GT[e][d] = G[d][e]
#define OFF_U    (2 * NB * 4096)             // [NB][NH][64][64]  U = Wk_h S Wk_h^T
#define OFF_PART ((2 * NB + NB * NH) * 4096) // [1024][4096]      per-block K^T V partials

// ---------------------------------------------------------------------------
// kA: per-block partial S over 64 rows. 1024 blocks (256/batch), 256 thr.
// Thread (di,ej) owns a 4x4 tile, contiguous f4 loads, NO LDS, NO atomics:
// each block stores its 16 KB partial with coalesced f4 stores.
// ---------------------------------------------------------------------------
__global__ __launch_bounds__(256) void kA(const float* __restrict__ keys,
                                          const float* __restrict__ values,
                                          float* __restrict__ part) {
    const int bid = blockIdx.x;
    const int b = bid >> 8;
    const int row0 = (bid & 255) * 64;
    const int t = threadIdx.x;
    const int di = t >> 4, ej = t & 15;
    const float* kp = keys   + ((size_t)b * SEQ + row0) * D + di * 4;
    const float* vp = values + ((size_t)b * SEQ + row0) * D + ej * 4;
    f4 acc[4];
    #pragma unroll
    for (int r = 0; r < 4; ++r) acc[r] = (f4)0.f;
    #pragma unroll 8
    for (int n = 0; n < 64; ++n) {
        f4 k4 = *(const f4*)(kp + n * D);
        f4 v4 = *(const f4*)(vp + n * D);
        #pragma unroll
        for (int r = 0; r < 4; ++r)
            acc[r] += k4[r] * v4;
    }
    float* pp = part + (size_t)bid * 4096;
    #pragma unroll
    for (int r = 0; r < 4; ++r)
        *(f4*)(pp + (di * 4 + r) * 64 + ej * 4) = acc[r];
}

// ---------------------------------------------------------------------------
// kB: reduce 256 partials/batch -> S[b]. 128 blocks = (b, quarter, p-chunk).
// Each block sums 32 partials over 1024 elements (f4/thread), then 4 scalar
// atomicAdds/thread into S (8-way contention, 131k atomics total).
// ---------------------------------------------------------------------------
__global__ __launch_bounds__(256) void kB(const float* __restrict__ part,
                                          float* __restrict__ S) {
    const int bid = blockIdx.x;
    const int b  = bid >> 5;
    const int q  = (bid >> 3) & 3;
    const int pc = bid & 7;
    const int t = threadIdx.x;
    const int e0 = q * 1024 + t * 4;
    const float* pp = part + (size_t)(b * 256 + pc * 32) * 4096 + e0;
    f4 s = (f4)0.f;
    #pragma unroll 8
    for (int p = 0; p < 32; ++p)
        s += *(const f4*)(pp + (size_t)p * 4096);
    float* Sb = S + b * 4096 + e0;
    #pragma unroll
    for (int i = 0; i < 4; ++i)
        atomicAdd(&Sb[i], s[i]);
}

// ---------------------------------------------------------------------------
// kC1: U[b,h] = Wk_h @ S[b] @ Wk_h^T.  32 blocks (b,h), 256 thr (16x16 grid,
// 4x4 tiles). Operands f4 from global (L2-resident); intermediate T in LDS
// stride-65 + di-rotated columns (<=2-way banks = free).
// ---------------------------------------------------------------------------
__global__ __launch_bounds__(256) void kC1(const float* __restrict__ Wk,
                                           float* __restrict__ ws) {
    __shared__ float T[64 * 65];
    const int b = blockIdx.x >> 3, h = blockIdx.x & 7;
    const int t = threadIdx.x;
    const int di = t >> 4, ej = t & 15;
    const float* Sb  = ws + OFF_S + b * 4096;
    const float* Wkh = Wk + (size_t)h * 64 * D;

    // m1: T[d][i] = sum_j Wk_h[d][j] * S[j][i]
    f4 acc[4];
    #pragma unroll
    for (int r = 0; r < 4; ++r) acc[r] = (f4)0.f;
    for (int j4 = 0; j4 < 16; ++j4) {
        f4 ak[4], bs[4];
        #pragma unroll
        for (int r = 0; r < 4; ++r)  ak[r] = *(const f4*)(Wkh + (di * 4 + r) * D + j4 * 4);
        #pragma unroll
        for (int jj = 0; jj < 4; ++jj) bs[jj] = *(const f4*)(Sb + (j4 * 4 + jj) * D + ej * 4);
        #pragma unroll
        for (int r = 0; r < 4; ++r)
            #pragma unroll
            for (int jj = 0; jj < 4; ++jj)
                acc[r] += ak[r][jj] * bs[jj];
    }
    #pragma unroll
    for (int r = 0; r < 4; ++r)
        #pragma unroll
        for (int c = 0; c < 4; ++c)
            T[(di * 4 + r) * 65 + ej * 4 + ((c + di) & 3)] = acc[r][c];
    __syncthreads();

    // m2: U[d][e] = sum_i T[d][i] * Wk_h[e][i]
    float a2[4][4];
    #pragma unroll
    for (int r = 0; r < 4; ++r)
        #pragma unroll
        for (int c = 0; c < 4; ++c) a2[r][c] = 0.f;
    for (int i4 = 0; i4 < 16; ++i4) {
        float av[4][4];
        f4 bw[4];
        #pragma unroll
        for (int ii = 0; ii < 4; ++ii)
            #pragma unroll
            for (int r = 0; r < 4; ++r)
                av[r][ii] = T[(di * 4 + r) * 65 + i4 * 4 + ((ii + di) & 3)];
        #pragma unroll
        for (int c = 0; c < 4; ++c)
            bw[c] = *(const f4*)(Wkh + (ej * 4 + c) * D + i4 * 4);
        #pragma unroll
        for (int r = 0; r < 4; ++r)
            #pragma unroll
            for (int c = 0; c < 4; ++c)
                #pragma unroll
                for (int ii = 0; ii < 4; ++ii)
                    a2[r][c] = fmaf(av[r][ii], bw[c][ii], a2[r][c]);
    }
    float* Up = ws + OFF_U + (size_t)(b * 8 + h) * 4096;
    #pragma unroll
    for (int r = 0; r < 4; ++r) {
        f4 o; o[0] = a2[r][0]; o[1] = a2[r][1]; o[2] = a2[r][2]; o[3] = a2[r][3];
        *(f4*)(Up + (di * 4 + r) * 64 + ej * 4) = o;
    }
}

// ---------------------------------------------------------------------------
// kC2: GT[b] += (1/N) * (Wq_h^T U[b,h] Wout_h^T)^T.  32 blocks (b,h).
// ---------------------------------------------------------------------------
__global__ __launch_bounds__(256) void kC2(const float* __restrict__ Wq,
                                           const float* __restrict__ Wout,
                                           float* __restrict__ ws) {
    __shared__ float T[64 * 65];
    const int b = blockIdx.x >> 3, h = blockIdx.x & 7;
    const int t = threadIdx.x;
    const int di = t >> 4, ej = t & 15;
    const float* Up = ws + OFF_U + (size_t)(b * 8 + h) * 4096;

    // m3: M3[d][e] = sum_i Wq[64h+i][d] * U[i][e]
    float acc[4][4];
    #pragma unroll
    for (int r = 0; r < 4; ++r)
        #pragma unroll
        for (int c = 0; c < 4; ++c) acc[r][c] = 0.f;
    for (int i4 = 0; i4 < 16; ++i4) {
        f4 wq4[4], bu[4];
        #pragma unroll
        for (int ii = 0; ii < 4; ++ii) {
            wq4[ii] = *(const f4*)(Wq + (size_t)(64 * h + i4 * 4 + ii) * D + di * 4);
            bu[ii]  = *(const f4*)(Up + (i4 * 4 + ii) * 64 + ej * 4);
        }
        #pragma unroll
        for (int r = 0; r < 4; ++r)
            #pragma unroll
            for (int c = 0; c < 4; ++c)
                #pragma unroll
                for (int ii = 0; ii < 4; ++ii)
                    acc[r][c] = fmaf(wq4[ii][r], bu[ii][c], acc[r][c]);
    }
    #pragma unroll
    for (int r = 0; r < 4; ++r)
        #pragma unroll
        for (int c = 0; c < 4; ++c)
            T[(di * 4 + r) * 65 + ej * 4 + ((c + di) & 3)] = acc[r][c];
    __syncthreads();

    // m4: Y[d][e] = sum_i M3[d][i] * Wout[e][64h+i]; GT[e][d] += Y/N
    float a2[4][4];
    #pragma unroll
    for (int r = 0; r < 4; ++r)
        #pragma unroll
        for (int c = 0; c < 4; ++c) a2[r][c] = 0.f;
    for (int i4 = 0; i4 < 16; ++i4) {
        float av[4][4];
        f4 bw[4];
        #pragma unroll
        for (int ii = 0; ii < 4; ++ii)
            #pragma unroll
            for (int r = 0; r < 4; ++r)
                av[r][ii] = T[(di * 4 + r) * 65 + i4 * 4 + ((ii + di) & 3)];
        #pragma unroll
        for (int c = 0; c < 4; ++c)
            bw[c] = *(const f4*)(Wout + (size_t)(ej * 4 + c) * INNER + 64 * h + i4 * 4);
        #pragma unroll
        for (int r = 0; r < 4; ++r)
            #pragma unroll
            for (int c = 0; c < 4; ++c)
                #pragma unroll
                for (int ii = 0; ii < 4; ++ii)
                    a2[r][c] = fmaf(av[r][ii], bw[c][ii], a2[r][c]);
    }
    const float invn = 1.0f / (float)SEQ;
    float* GTb = ws + OFF_GT + b * 4096;
    #pragma unroll
    for (int r = 0; r < 4; ++r)
        #pragma unroll
        for (int c = 0; c < 4; ++c)
            atomicAdd(&GTb[(ej * 4 + c) * 64 + di * 4 + r], a2[r][c] * invn);
}

// ---------------------------------------------------------------------------
// kE: out[n][e] = q[n][:] . G[:][e] + bout[e] via GT (f4 over d, L1-resident).
// 1024 blocks x 64 rows, no LDS. Lane tile: 4 contiguous rows x 4 cols.
// ---------------------------------------------------------------------------
__global__ __launch_bounds__(256) void kE(const float* __restrict__ queries,
                                          const float* __restrict__ bout,
                                          const float* __restrict__ ws,
                                          float* __restrict__ out) {
    const int bid = blockIdx.x;
    const int b = bid >> 8;
    const int row0 = (bid & 255) * 64;
    const int t = threadIdx.x;
    const int w = t >> 6, l = t & 63;
    const int rg = l >> 4, eg = l & 15;
    const float* GT = ws + OFF_GT + b * 4096;
    const size_t rbase = (size_t)b * SEQ + row0 + w * 16 + rg * 4;
    const float* qp = queries + rbase * D;
    float acc[4][4];
    #pragma unroll
    for (int r = 0; r < 4; ++r)
        #pragma unroll
        for (int c = 0; c < 4; ++c) acc[r][c] = 0.f;
    #pragma unroll 2
    for (int dq = 0; dq < 16; ++dq) {
        f4 q4[4], g4[4];
        #pragma unroll
        for (int r = 0; r < 4; ++r)
            q4[r] = *(const f4*)(qp + r * D + dq * 4);
        #pragma unroll
        for (int c = 0; c < 4; ++c)
            g4[c] = *(const f4*)(GT + (eg * 4 + c) * 64 + dq * 4);
        #pragma unroll
        for (int r = 0; r < 4; ++r)
            #pragma unroll
            for (int c = 0; c < 4; ++c)
                #pragma unroll
                for (int ii = 0; ii < 4; ++ii)
                    acc[r][c] = fmaf(q4[r][ii], g4[c][ii], acc[r][c]);
    }
    const f4 bo = *(const f4*)(bout + eg * 4);
    float* op = out + rbase * D;
    #pragma unroll
    for (int r = 0; r < 4; ++r) {
        f4 o;
        o[0] = acc[r][0] + bo[0]; o[1] = acc[r][1] + bo[1];
        o[2] = acc[r][2] + bo[2]; o[3] = acc[r][3] + bo[3];
        *(f4*)(op + r * D + eg * 4) = o;
    }
}

extern "C" void kernel_launch(void* const* d_in, const int* in_sizes, int n_in,
                              void* d_out, int out_size, void* d_ws, size_t ws_size,
                              hipStream_t stream) {
    const float* queries = (const float*)d_in[0];
    const float* keys    = (const float*)d_in[1];
    const float* values  = (const float*)d_in[2];
    const float* Wq      = (const float*)d_in[3];
    const float* Wk      = (const float*)d_in[4];
    const float* Wout    = (const float*)d_in[5];
    const float* bout    = (const float*)d_in[6];
    float* ws = (float*)d_ws;

    // zero S + GT (atomic accumulation targets)
    hipMemsetAsync(ws, 0, (size_t)2 * NB * 4096 * sizeof(float), stream);

    kA <<<1024, 256, 0, stream>>>(keys, values, ws + OFF_PART);
    kB <<<128,  256, 0, stream>>>(ws + OFF_PART, ws + OFF_S);
    kC1<<<32,   256, 0, stream>>>(Wk, ws);
    kC2<<<32,   256, 0, stream>>>(Wq, Wout, ws);
    kE <<<1024, 256, 0, stream>>>(queries, bout, ws, (float*)d_out);
}